// Round 1
// baseline (49763.446 us; speedup 1.0000x reference)
//
#include <hip/hip_runtime.h>
#include <hip/hip_bf16.h>

#define NN 384
#define CIN 128
#define NH 4
#define CH 32
#define INFB 1e9f
#define QSCALE 0.17677669529663687f

__device__ __forceinline__ float bf2f(unsigned short u) {
    return __uint_as_float(((unsigned int)u) << 16);
}
__device__ __forceinline__ unsigned short f2bf(float f) {
    unsigned int u = __float_as_uint(f);
    u += 0x7fffu + ((u >> 16) & 1u);
    return (unsigned short)(u >> 16);
}

// ---------------------------------------------------------------------------
// Kernel 1: LayerNorm + projections q,k,v,g (+ tri) for 32 positions/block
// ---------------------------------------------------------------------------
__global__ __launch_bounds__(256) void ln_proj_kernel(
    const float* __restrict__ z, const float* __restrict__ lnw, const float* __restrict__ lnb,
    const float* __restrict__ wtri, const float* __restrict__ wq, const float* __restrict__ wk,
    const float* __restrict__ wv, const float* __restrict__ wg,
    unsigned short* __restrict__ qb, unsigned short* __restrict__ kb,
    unsigned short* __restrict__ vb, unsigned short* __restrict__ gb,
    float* __restrict__ tri)
{
    __shared__ float zt[32 * CIN];     // 16 KB
    __shared__ float mu_s[32], rs_s[32];
    const int t = threadIdx.x;
    const long base = (long)blockIdx.x * (32 * CIN);

    #pragma unroll
    for (int r = 0; r < 16; ++r) zt[t + 256 * r] = z[base + t + 256 * r];
    __syncthreads();

    {   // LN stats: 8 threads per position
        int p = t >> 3, s = t & 7;
        float sum = 0.f, sq = 0.f;
        #pragma unroll
        for (int c = s; c < CIN; c += 8) { float x = zt[p * CIN + c]; sum += x; sq += x * x; }
        #pragma unroll
        for (int m = 1; m < 8; m <<= 1) { sum += __shfl_xor(sum, m); sq += __shfl_xor(sq, m); }
        if (s == 0) {
            float mu = sum * (1.f / CIN);
            float var = sq * (1.f / CIN) - mu * mu;
            mu_s[p] = mu; rs_s[p] = rsqrtf(var + 1e-5f);
        }
    }
    __syncthreads();
    #pragma unroll
    for (int r = 0; r < 16; ++r) {
        int idx = t + 256 * r; int p = idx >> 7, c = idx & 127;
        zt[idx] = (zt[idx] - mu_s[p]) * rs_s[p] * lnw[c] + lnb[c];
    }
    __syncthreads();

    // projections, 4x4 register blocking: cols 4*cg..+3, positions pgr*4..+3
    const int cg = t & 31, pgr = t >> 5;
    int posi[4], posj[4];
    #pragma unroll
    for (int p = 0; p < 4; ++p) {
        int pos = blockIdx.x * 32 + pgr * 4 + p;
        posi[p] = pos / NN; posj[p] = pos - posi[p] * NN;
    }
    const float* Ws[4] = { wq, wk, wv, wg };

    #pragma unroll 1
    for (int m = 0; m < 4; ++m) {
        const float* __restrict__ W = Ws[m];
        float acc[4][4];
        #pragma unroll
        for (int p = 0; p < 4; ++p)
            #pragma unroll
            for (int x = 0; x < 4; ++x) acc[p][x] = 0.f;

        for (int ci4 = 0; ci4 < CIN / 4; ++ci4) {
            float4 w[4];
            #pragma unroll
            for (int x = 0; x < 4; ++x)
                w[x] = *reinterpret_cast<const float4*>(&W[(ci4 * 4 + x) * CIN + cg * 4]);
            #pragma unroll
            for (int p = 0; p < 4; ++p) {
                const float4 zv = *reinterpret_cast<const float4*>(&zt[(pgr * 4 + p) * CIN + ci4 * 4]);
                #pragma unroll
                for (int c = 0; c < 4; ++c) {
                    float wc0 = (c == 0) ? w[0].x : (c == 1) ? w[0].y : (c == 2) ? w[0].z : w[0].w;
                    float wc1 = (c == 0) ? w[1].x : (c == 1) ? w[1].y : (c == 2) ? w[1].z : w[1].w;
                    float wc2 = (c == 0) ? w[2].x : (c == 1) ? w[2].y : (c == 2) ? w[2].z : w[2].w;
                    float wc3 = (c == 0) ? w[3].x : (c == 1) ? w[3].y : (c == 2) ? w[3].z : w[3].w;
                    acc[p][c] = fmaf(zv.x, wc0, acc[p][c]);
                    acc[p][c] = fmaf(zv.y, wc1, acc[p][c]);
                    acc[p][c] = fmaf(zv.z, wc2, acc[p][c]);
                    acc[p][c] = fmaf(zv.w, wc3, acc[p][c]);
                }
            }
        }
        // store
        #pragma unroll
        for (int p = 0; p < 4; ++p) {
            #pragma unroll
            for (int x = 0; x < 4; ++x) {
                int col = cg * 4 + x;
                if (m < 3) {
                    int hh = col >> 5, cc = col & 31;
                    long o = (((long)(posi[p] * NH + hh)) * NN + posj[p]) * CH + cc;
                    if (m == 0)      qb[o] = f2bf(acc[p][x] * QSCALE);
                    else if (m == 1) kb[o] = f2bf(acc[p][x]);
                    else             vb[o] = f2bf(acc[p][x]);
                } else {
                    long pos = (long)blockIdx.x * 32 + pgr * 4 + p;
                    gb[pos * CIN + col] = f2bf(1.f / (1.f + __expf(-acc[p][x])));
                }
            }
        }
    }

    // tri: 128 threads, one (pos, head) each over 32 pos x 4 heads
    if (t < 128) {
        int p = t >> 2, hh = t & 3;
        float acc = 0.f;
        for (int ci = 0; ci < CIN; ++ci) acc = fmaf(zt[p * CIN + ci], wtri[ci * NH + hh], acc);
        long pos = (long)blockIdx.x * 32 + p;
        tri[pos * NH + hh] = acc;
    }
}

// ---------------------------------------------------------------------------
// Kernel 2: attention per (i, h). K,V in LDS; scores/softmax/PV in registers.
// Thread (qi, ksx): q-row qi (16 per tile), k-strided set ksx,ksx+16,...
// ---------------------------------------------------------------------------
__global__ __launch_bounds__(256) void attn_kernel(
    const unsigned short* __restrict__ qb, const unsigned short* __restrict__ kb,
    const unsigned short* __restrict__ vb, const float* __restrict__ tri,
    const float* __restrict__ mask, float* __restrict__ ob)
{
    constexpr int KPAD = 34;   // bf16 elems/row: 17 dwords -> conflict-free strided rows
    __shared__ unsigned short ks[NN * KPAD];  // 26.1 KB
    __shared__ unsigned short vs[NN * KPAD];  // 26.1 KB
    __shared__ float bias[NN];

    const int t = threadIdx.x;
    const int i = blockIdx.x >> 2, h = blockIdx.x & 3;
    const long hb = ((long)i * NH + h) * NN * CH;

    {
        const unsigned int* ksrc = reinterpret_cast<const unsigned int*>(kb + hb);
        const unsigned int* vsrc = reinterpret_cast<const unsigned int*>(vb + hb);
        for (int idx = t; idx < NN * 16; idx += 256) {
            int kk = idx >> 4, c2 = idx & 15;
            *reinterpret_cast<unsigned int*>(&ks[kk * KPAD + 2 * c2]) = ksrc[idx];
            *reinterpret_cast<unsigned int*>(&vs[kk * KPAD + 2 * c2]) = vsrc[idx];
        }
        for (int idx = t; idx < NN; idx += 256)
            bias[idx] = INFB * (mask[(long)i * NN + idx] - 1.0f);
    }
    __syncthreads();

    const int qi = t >> 4, ksx = t & 15;

    #pragma unroll 1
    for (int qt = 0; qt < NN / 16; ++qt) {
        const int qpos = qt * 16 + qi;

        // q row -> registers (16-lane redundant loads, L1 broadcast)
        float qreg[32];
        {
            const unsigned int* qsrc = reinterpret_cast<const unsigned int*>(qb + hb + (long)qpos * CH);
            #pragma unroll
            for (int c2 = 0; c2 < 16; ++c2) {
                unsigned int u = qsrc[c2];
                qreg[2 * c2]     = bf2f((unsigned short)(u & 0xffffu));
                qreg[2 * c2 + 1] = bf2f((unsigned short)(u >> 16));
            }
        }

        // scores (24 per thread)
        float sreg[24];
        const float* trow = tri + (long)qpos * NN * NH + h;
        #pragma unroll
        for (int idx = 0; idx < 24; ++idx) {
            const int kk = ksx + 16 * idx;
            float acc0 = bias[kk] + trow[kk * NH];
            float acc1 = 0.f;
            const unsigned int* kp = reinterpret_cast<const unsigned int*>(&ks[kk * KPAD]);
            #pragma unroll
            for (int c2 = 0; c2 < 16; c2 += 2) {
                unsigned int u0 = kp[c2], u1 = kp[c2 + 1];
                acc0 = fmaf(qreg[2 * c2],     bf2f((unsigned short)(u0 & 0xffffu)), acc0);
                acc0 = fmaf(qreg[2 * c2 + 1], bf2f((unsigned short)(u0 >> 16)),     acc0);
                acc1 = fmaf(qreg[2 * c2 + 2], bf2f((unsigned short)(u1 & 0xffffu)), acc1);
                acc1 = fmaf(qreg[2 * c2 + 3], bf2f((unsigned short)(u1 >> 16)),     acc1);
            }
            sreg[idx] = acc0 + acc1;
        }

        // softmax across 24 local x 16 lanes
        float mx = sreg[0];
        #pragma unroll
        for (int idx = 1; idx < 24; ++idx) mx = fmaxf(mx, sreg[idx]);
        #pragma unroll
        for (int msk = 1; msk < 16; msk <<= 1) mx = fmaxf(mx, __shfl_xor(mx, msk));
        float sum = 0.f;
        #pragma unroll
        for (int idx = 0; idx < 24; ++idx) { float p = __expf(sreg[idx] - mx); sreg[idx] = p; sum += p; }
        #pragma unroll
        for (int msk = 1; msk < 16; msk <<= 1) sum += __shfl_xor(sum, msk);
        const float iv = 1.0f / sum;

        // PV partials
        float o[32];
        #pragma unroll
        for (int c = 0; c < 32; ++c) o[c] = 0.f;
        #pragma unroll
        for (int idx = 0; idx < 24; ++idx) {
            const int kk = ksx + 16 * idx;
            const float p = sreg[idx];
            const unsigned int* vp = reinterpret_cast<const unsigned int*>(&vs[kk * KPAD]);
            #pragma unroll
            for (int c2 = 0; c2 < 16; ++c2) {
                unsigned int u = vp[c2];
                o[2 * c2]     = fmaf(p, bf2f((unsigned short)(u & 0xffffu)), o[2 * c2]);
                o[2 * c2 + 1] = fmaf(p, bf2f((unsigned short)(u >> 16)),     o[2 * c2 + 1]);
            }
        }

        // reduce-scatter across the 16 lanes sharing this q-row
        int base = 0;
        #pragma unroll
        for (int s = 0; s < 4; ++s) {
            const int m2 = 1 << s;
            const int half = 16 >> s;      // 16,8,4,2
            const bool hi = (ksx >> s) & 1;
            const int keep = hi ? half : 0;
            const int send = hi ? 0 : half;
            #pragma unroll
            for (int x = 0; x < half; ++x) {
                float other = __shfl_xor(o[send + x], m2);
                o[x] = o[keep + x] + other;
            }
            if (hi) base += half;
        }
        // o[0],o[1] are channels base, base+1
        float2 o2; o2.x = o[0] * iv; o2.y = o[1] * iv;
        *reinterpret_cast<float2*>(&ob[hb + (long)qpos * CH + base]) = o2;
    }
}

// ---------------------------------------------------------------------------
// Kernel 3: out = (o * g) @ wo, 32 positions/block, 4x4 register blocking
// ---------------------------------------------------------------------------
__global__ __launch_bounds__(256) void out_kernel(
    const float* __restrict__ ob, const unsigned short* __restrict__ gb,
    const float* __restrict__ wo, float* __restrict__ out)
{
    __shared__ float og[32 * CIN];  // 16 KB
    const int t = threadIdx.x;
    const long pbase = (long)blockIdx.x * 32;

    #pragma unroll
    for (int r = 0; r < 16; ++r) {
        int idx = t + 256 * r; int p = idx >> 7, hc = idx & 127;
        long pos = pbase + p;
        int ii = (int)(pos / NN); int jj = (int)(pos - (long)ii * NN);
        int hh = hc >> 5, cc = hc & 31;
        float o = ob[(((long)(ii * NH + hh)) * NN + jj) * CH + cc];
        float g = bf2f(gb[pos * CIN + hc]);
        og[p * CIN + hc] = o * g;
    }
    __syncthreads();

    const int cg = t & 31, pgr = t >> 5;
    float acc[4][4];
    #pragma unroll
    for (int p = 0; p < 4; ++p)
        #pragma unroll
        for (int x = 0; x < 4; ++x) acc[p][x] = 0.f;

    for (int ci4 = 0; ci4 < CIN / 4; ++ci4) {
        float4 w[4];
        #pragma unroll
        for (int x = 0; x < 4; ++x)
            w[x] = *reinterpret_cast<const float4*>(&wo[(ci4 * 4 + x) * CIN + cg * 4]);
        #pragma unroll
        for (int p = 0; p < 4; ++p) {
            const float4 zv = *reinterpret_cast<const float4*>(&og[(pgr * 4 + p) * CIN + ci4 * 4]);
            #pragma unroll
            for (int c = 0; c < 4; ++c) {
                float wc0 = (c == 0) ? w[0].x : (c == 1) ? w[0].y : (c == 2) ? w[0].z : w[0].w;
                float wc1 = (c == 0) ? w[1].x : (c == 1) ? w[1].y : (c == 2) ? w[1].z : w[1].w;
                float wc2 = (c == 0) ? w[2].x : (c == 1) ? w[2].y : (c == 2) ? w[2].z : w[2].w;
                float wc3 = (c == 0) ? w[3].x : (c == 1) ? w[3].y : (c == 2) ? w[3].z : w[3].w;
                acc[p][c] = fmaf(zv.x, wc0, acc[p][c]);
                acc[p][c] = fmaf(zv.y, wc1, acc[p][c]);
                acc[p][c] = fmaf(zv.z, wc2, acc[p][c]);
                acc[p][c] = fmaf(zv.w, wc3, acc[p][c]);
            }
        }
    }
    #pragma unroll
    for (int p = 0; p < 4; ++p) {
        long pos = pbase + pgr * 4 + p;
        float4 v4; v4.x = acc[p][0]; v4.y = acc[p][1]; v4.z = acc[p][2]; v4.w = acc[p][3];
        *reinterpret_cast<float4*>(&out[pos * CIN + cg * 4]) = v4;
    }
}

// ---------------------------------------------------------------------------
extern "C" void kernel_launch(void* const* d_in, const int* in_sizes, int n_in,
                              void* d_out, int out_size, void* d_ws, size_t ws_size,
                              hipStream_t stream)
{
    const float* z    = (const float*)d_in[0];
    const float* mask = (const float*)d_in[1];
    const float* lnw  = (const float*)d_in[2];
    const float* lnb  = (const float*)d_in[3];
    const float* wtri = (const float*)d_in[4];
    const float* wq   = (const float*)d_in[5];
    const float* wk   = (const float*)d_in[6];
    const float* wv   = (const float*)d_in[7];
    const float* wg   = (const float*)d_in[8];
    const float* wo   = (const float*)d_in[9];
    float* out = (float*)d_out;

    char* ws = (char*)d_ws;
    size_t off = 0;
    auto carve = [&](size_t bytes) -> void* {
        void* p = ws + off; off += (bytes + 255) & ~size_t(255); return p;
    };
    const size_t nelem = (size_t)NN * NN * CIN;  // 18,874,368
    unsigned short* qb = (unsigned short*)carve(nelem * 2);
    unsigned short* kb = (unsigned short*)carve(nelem * 2);
    unsigned short* vb = (unsigned short*)carve(nelem * 2);
    unsigned short* gb = (unsigned short*)carve(nelem * 2);
    float* tri = (float*)carve((size_t)NN * NN * NH * 4);
    float* ob  = (float*)carve(nelem * 4);
    (void)ws_size; (void)in_sizes; (void)n_in; (void)out_size;

    hipLaunchKernelGGL(ln_proj_kernel, dim3(NN * NN / 32), dim3(256), 0, stream,
                       z, lnw, lnb, wtri, wq, wk, wv, wg, qb, kb, vb, gb, tri);
    hipLaunchKernelGGL(attn_kernel, dim3(NN * NH), dim3(256), 0, stream,
                       qb, kb, vb, tri, mask, ob);
    hipLaunchKernelGGL(out_kernel, dim3(NN * NN / 32), dim3(256), 0, stream,
                       ob, gb, wo, out);
}

// Round 2
// 460.810 us; speedup vs baseline: 107.9912x; 107.9912x over previous
//
#include <hip/hip_runtime.h>
#include <hip/hip_bf16.h>

#define NN 384
#define CIN 128
#define NH 4
#define CH 32
#define NPOS (NN * NN)      // 147456
#define INFB 1e9f
#define QSCALE 0.17677669529663687f

typedef float f32x4 __attribute__((ext_vector_type(4)));
typedef short short8 __attribute__((ext_vector_type(8)));

__device__ __forceinline__ float bf2f(unsigned short u) {
    return __uint_as_float(((unsigned int)u) << 16);
}
__device__ __forceinline__ unsigned short f2bf(float f) {
    unsigned int u = __float_as_uint(f);
    u += 0x7fffu + ((u >> 16) & 1u);
    return (unsigned short)(u >> 16);
}
__device__ __forceinline__ unsigned int pack2bf(float a, float b) {
    return (unsigned int)f2bf(a) | ((unsigned int)f2bf(b) << 16);
}

// ---------------------------------------------------------------------------
// Kernel 1: LayerNorm -> zn (bf16, [pos][128]) + tri (bf16, [h][pos])
// ---------------------------------------------------------------------------
__global__ __launch_bounds__(256) void ln_kernel(
    const float* __restrict__ z, const float* __restrict__ lnw, const float* __restrict__ lnb,
    const float* __restrict__ wtri,
    unsigned short* __restrict__ zn, unsigned short* __restrict__ trib)
{
    __shared__ float zt[32 * CIN];
    __shared__ float mu_s[32], rs_s[32];
    __shared__ float wt_s[CIN * NH];
    const int t = threadIdx.x;
    const long base = (long)blockIdx.x * (32 * CIN);

    #pragma unroll
    for (int r = 0; r < 16; ++r) zt[t + 256 * r] = z[base + t + 256 * r];
    wt_s[t] = wtri[t]; wt_s[t + 256] = wtri[t + 256];
    __syncthreads();

    {   // stats: 8 threads per position
        int p = t >> 3, s = t & 7;
        float sum = 0.f, sq = 0.f;
        for (int c = s; c < CIN; c += 8) { float x = zt[p * CIN + c]; sum += x; sq += x * x; }
        #pragma unroll
        for (int m = 1; m < 8; m <<= 1) { sum += __shfl_xor(sum, m); sq += __shfl_xor(sq, m); }
        if (s == 0) {
            float mu = sum * (1.f / CIN);
            float var = sq * (1.f / CIN) - mu * mu;
            mu_s[p] = mu; rs_s[p] = rsqrtf(var + 1e-5f);
        }
    }
    __syncthreads();
    #pragma unroll
    for (int r = 0; r < 16; ++r) {
        int idx = t + 256 * r; int p = idx >> 7, c = idx & 127;
        zt[idx] = (zt[idx] - mu_s[p]) * rs_s[p] * lnw[c] + lnb[c];
    }
    __syncthreads();

    // zn store, bf16 pairs packed in u32, coalesced
    unsigned int* zno = (unsigned int*)zn + (long)blockIdx.x * 2048;
    #pragma unroll
    for (int r = 0; r < 8; ++r) {
        int i32 = t + 256 * r;
        zno[i32] = pack2bf(zt[2 * i32], zt[2 * i32 + 1]);
    }

    // tri: 128 threads, (h = t>>5, p = t&31); rotated ci to avoid bank conflicts
    if (t < 128) {
        int h = t >> 5, p = t & 31;
        float acc = 0.f;
        #pragma unroll 8
        for (int ii = 0; ii < CIN; ++ii) {
            int ci = (p + ii) & 127;
            acc = fmaf(zt[p * CIN + ci], wt_s[ci * NH + h], acc);
        }
        trib[(long)h * NPOS + (long)blockIdx.x * 32 + p] = f2bf(acc);
    }
}

// ---------------------------------------------------------------------------
// Kernel 2: weight convert: wcat[m][n][k] = W_m[k][n] (bf16, q pre-scaled),
//           wot[n][k] = wo[k][n]
// ---------------------------------------------------------------------------
__global__ __launch_bounds__(256) void wconv_kernel(
    const float* __restrict__ wq, const float* __restrict__ wk, const float* __restrict__ wv,
    const float* __restrict__ wg, const float* __restrict__ wo,
    unsigned short* __restrict__ wcat, unsigned short* __restrict__ wot)
{
    const int m = blockIdx.x, t = threadIdx.x;
    const float* W = (m == 0) ? wq : (m == 1) ? wk : (m == 2) ? wv : (m == 3) ? wg : wo;
    const float s = (m == 0) ? QSCALE : 1.0f;
    unsigned short* dst = (m < 4) ? (wcat + m * CIN * CIN) : wot;
    for (int idx = t; idx < CIN * CIN; idx += 256) {
        int n = idx >> 7, k = idx & 127;
        dst[idx] = f2bf(W[k * CIN + n] * s);
    }
}

// ---------------------------------------------------------------------------
// 128x128x128 MFMA tile core. A: [128 rows m][128 k] bf16 row-major.
// B: [128 rows n][128 k] bf16 row-major (i.e. W^T). XOR-swizzled LDS.
// ---------------------------------------------------------------------------
__device__ __forceinline__ void gemm128_core(
    const unsigned short* __restrict__ Ag, const unsigned short* __restrict__ Bg,
    unsigned short* lsA, unsigned short* lsB, f32x4 acc[4][4], int t)
{
    const int lane = t & 63, w = t >> 6, l15 = lane & 15, hi = lane >> 4;
    #pragma unroll
    for (int it = 0; it < 8; ++it) {
        int row = w * 32 + it * 4 + hi;
        int cb = l15 * 16;
        uint4 va = *(const uint4*)((const char*)Ag + row * 256 + cb);
        uint4 vb = *(const uint4*)((const char*)Bg + row * 256 + cb);
        int sw = cb ^ ((row & 7) << 4);
        *(uint4*)((char*)lsA + row * 256 + sw) = va;
        *(uint4*)((char*)lsB + row * 256 + sw) = vb;
    }
    __syncthreads();
    const int wm = (w >> 1) * 64, wn = (w & 1) * 64;
    #pragma unroll
    for (int kk = 0; kk < 4; ++kk) {
        short8 a[4], b[4];
        #pragma unroll
        for (int f = 0; f < 4; ++f) {
            int ra = wm + f * 16 + l15;
            int rb = wn + f * 16 + l15;
            int c = kk * 64 + hi * 16;
            a[f] = *(const short8*)((const char*)lsA + ra * 256 + (c ^ ((ra & 7) << 4)));
            b[f] = *(const short8*)((const char*)lsB + rb * 256 + (c ^ ((rb & 7) << 4)));
        }
        #pragma unroll
        for (int mf = 0; mf < 4; ++mf)
            #pragma unroll
            for (int nf = 0; nf < 4; ++nf)
                acc[mf][nf] = __builtin_amdgcn_mfma_f32_16x16x32_bf16(a[mf], b[nf], acc[mf][nf], 0, 0, 0);
    }
}

// ---------------------------------------------------------------------------
// Kernel 3: projections GEMM. grid (1152, 4); y = matrix (q,k,v,g)
// ---------------------------------------------------------------------------
__global__ __launch_bounds__(256) void proj_gemm_kernel(
    const unsigned short* __restrict__ zn, const unsigned short* __restrict__ wcat,
    unsigned short* __restrict__ qb, unsigned short* __restrict__ kb,
    unsigned short* __restrict__ vb, unsigned short* __restrict__ gb)
{
    __shared__ alignas(16) unsigned short lsA[128 * 128];
    __shared__ alignas(16) unsigned short lsB[128 * 128];
    const int t = threadIdx.x;
    const int mb = blockIdx.x, mat = blockIdx.y;
    f32x4 acc[4][4];
    #pragma unroll
    for (int i = 0; i < 4; ++i)
        #pragma unroll
        for (int j = 0; j < 4; ++j) acc[i][j] = (f32x4){0.f, 0.f, 0.f, 0.f};
    gemm128_core(zn + (long)mb * 128 * 128, wcat + mat * 128 * 128, lsA, lsB, acc, t);

    const int lane = t & 63, w = t >> 6, l15 = lane & 15, hi = lane >> 4;
    const int wm = (w >> 1) * 64, wn = (w & 1) * 64;
    unsigned short* dst = (mat == 0) ? qb : (mat == 1) ? kb : (mat == 2) ? vb : gb;
    #pragma unroll
    for (int mf = 0; mf < 4; ++mf)
        #pragma unroll
        for (int nf = 0; nf < 4; ++nf)
            #pragma unroll
            for (int r = 0; r < 4; ++r) {
                long pos = (long)mb * 128 + wm + mf * 16 + hi * 4 + r;
                int n = wn + nf * 16 + l15;
                float v = acc[mf][nf][r];
                if (mat == 3) v = 1.f / (1.f + __expf(-v));
                dst[pos * CIN + n] = f2bf(v);
            }
}

// ---------------------------------------------------------------------------
// Kernel 4: MFMA attention per (i,h). K/V^T/bias in LDS; softmax in regs;
// P via per-wave LDS; 1/sum folded into O epilogue.
// ---------------------------------------------------------------------------
__global__ __launch_bounds__(256) void attn_kernel(
    const unsigned short* __restrict__ qb, const unsigned short* __restrict__ kb,
    const unsigned short* __restrict__ vb, const unsigned short* __restrict__ trib,
    const float* __restrict__ mask, unsigned short* __restrict__ ob)
{
    constexpr int KP = 40;    // K row pad (elems): 80 B rows, 16B aligned
    constexpr int VP = 392;   // V^T row pad: 784 B rows
    constexpr int PP = 392;   // P row pad
    __shared__ alignas(16) unsigned short Ks[NN * KP];      // 30720 B
    __shared__ alignas(16) unsigned short VTs[CH * VP];     // 25088 B
    __shared__ alignas(16) unsigned short Ps[4][16 * PP];   // 50176 B (per-wave)
    __shared__ float biasS[NN];

    const int t = threadIdx.x;
    const int i = blockIdx.x >> 2, h = blockIdx.x & 3;
    const long rowbase = (long)i * NN;

    {   // stage K (u32 chunks), V^T (u16 transpose), bias
        const unsigned int* ksrc = (const unsigned int*)kb + rowbase * (CIN / 2) + h * (CH / 2);
        for (int idx = t; idx < NN * 16; idx += 256) {
            int row = idx >> 4, c2 = idx & 15;
            *(unsigned int*)&Ks[row * KP + c2 * 2] = ksrc[(long)row * 64 + c2];
        }
        for (int idx = t; idx < CH * NN; idx += 256) {
            int n = idx >> 5, c = idx & 31;
            VTs[c * VP + n] = vb[(rowbase + n) * CIN + h * CH + c];
        }
        for (int idx = t; idx < NN; idx += 256)
            biasS[idx] = INFB * (mask[rowbase + idx] - 1.f);
    }
    __syncthreads();

    const int lane = t & 63, w = t >> 6, l15 = lane & 15, hi = lane >> 4;
    unsigned short* Pw = Ps[w];
    const f32x4 zero4 = {0.f, 0.f, 0.f, 0.f};

    for (int mt = w; mt < NN / 16; mt += 4) {
        const int q0 = mt * 16;

        // stage tri tile [16][384] bf16 -> Pw (linear region), contiguous global
        {
            const uint4* tsrc = (const uint4*)(trib + (long)h * NPOS + (long)q0 * NN);
            uint4* tdst = (uint4*)Pw;
            #pragma unroll
            for (int it = 0; it < 12; ++it)
                tdst[it * 64 + lane] = tsrc[it * 64 + lane];
        }

        // Q fragment (global, coalesced 64B rows)
        const short8 aq = *(const short8*)(qb + (rowbase + q0 + l15) * CIN + h * CH + hi * 8);

        // QK^T: 24 n-fragments
        f32x4 acc[24];
        #pragma unroll
        for (int nf = 0; nf < 24; ++nf) {
            const short8 bk = *(const short8*)&Ks[(nf * 16 + l15) * KP + hi * 8];
            acc[nf] = __builtin_amdgcn_mfma_f32_16x16x32_bf16(aq, bk, zero4, 0, 0, 0);
        }

        // bias + tri, rowmax
        float mx[4] = {-1e30f, -1e30f, -1e30f, -1e30f};
        #pragma unroll
        for (int nf = 0; nf < 24; ++nf)
            #pragma unroll
            for (int r = 0; r < 4; ++r) {
                float s = acc[nf][r] + biasS[nf * 16 + l15]
                        + bf2f(Pw[(4 * hi + r) * 384 + nf * 16 + l15]);
                acc[nf][r] = s;
                mx[r] = fmaxf(mx[r], s);
            }
        #pragma unroll
        for (int m2 = 1; m2 < 16; m2 <<= 1)
            #pragma unroll
            for (int r = 0; r < 4; ++r) mx[r] = fmaxf(mx[r], __shfl_xor(mx[r], m2));

        float sum[4] = {0.f, 0.f, 0.f, 0.f};
        #pragma unroll
        for (int nf = 0; nf < 24; ++nf)
            #pragma unroll
            for (int r = 0; r < 4; ++r) {
                float e = __expf(acc[nf][r] - mx[r]);
                acc[nf][r] = e; sum[r] += e;
            }
        #pragma unroll
        for (int m2 = 1; m2 < 16; m2 <<= 1)
            #pragma unroll
            for (int r = 0; r < 4; ++r) sum[r] += __shfl_xor(sum[r], m2);
        float inv[4];
        #pragma unroll
        for (int r = 0; r < 4; ++r) inv[r] = 1.f / sum[r];

        // write unnormalized P (bf16) to padded region
        #pragma unroll
        for (int nf = 0; nf < 24; ++nf)
            #pragma unroll
            for (int r = 0; r < 4; ++r)
                Pw[(4 * hi + r) * PP + nf * 16 + l15] = f2bf(acc[nf][r]);

        // PV: O[16][32] over 12 k-steps
        f32x4 o0 = zero4, o1 = zero4;
        #pragma unroll
        for (int ks = 0; ks < 12; ++ks) {
            const short8 ap  = *(const short8*)&Pw[l15 * PP + ks * 32 + hi * 8];
            const short8 bv0 = *(const short8*)&VTs[l15 * VP + ks * 32 + hi * 8];
            const short8 bv1 = *(const short8*)&VTs[(16 + l15) * VP + ks * 32 + hi * 8];
            o0 = __builtin_amdgcn_mfma_f32_16x16x32_bf16(ap, bv0, o0, 0, 0, 0);
            o1 = __builtin_amdgcn_mfma_f32_16x16x32_bf16(ap, bv1, o1, 0, 0, 0);
        }

        // epilogue: normalize by inv[r], store bf16
        #pragma unroll
        for (int r = 0; r < 4; ++r) {
            long qrow = rowbase + q0 + 4 * hi + r;
            ob[qrow * CIN + h * CH + l15]      = f2bf(o0[r] * inv[r]);
            ob[qrow * CIN + h * CH + 16 + l15] = f2bf(o1[r] * inv[r]);
        }
    }
}

// ---------------------------------------------------------------------------
// Kernel 5: og = o * g elementwise (bf16), grid-stride
// ---------------------------------------------------------------------------
__global__ __launch_bounds__(256) void og_kernel(
    const unsigned int* __restrict__ ob, const unsigned int* __restrict__ gb,
    unsigned int* __restrict__ og)
{
    const int n32 = NPOS * CIN / 2;
    for (long idx = (long)blockIdx.x * 256 + threadIdx.x; idx < n32; idx += (long)gridDim.x * 256) {
        unsigned int o = ob[idx], g = gb[idx];
        og[idx] = pack2bf(bf2f((unsigned short)o) * bf2f((unsigned short)g),
                          bf2f((unsigned short)(o >> 16)) * bf2f((unsigned short)(g >> 16)));
    }
}

// ---------------------------------------------------------------------------
// Kernel 6: out = og @ wo (fp32 out). grid (1152)
// ---------------------------------------------------------------------------
__global__ __launch_bounds__(256) void out_gemm_kernel(
    const unsigned short* __restrict__ og, const unsigned short* __restrict__ wot,
    float* __restrict__ out)
{
    __shared__ alignas(16) unsigned short lsA[128 * 128];
    __shared__ alignas(16) unsigned short lsB[128 * 128];
    const int t = threadIdx.x;
    const int mb = blockIdx.x;
    f32x4 acc[4][4];
    #pragma unroll
    for (int i = 0; i < 4; ++i)
        #pragma unroll
        for (int j = 0; j < 4; ++j) acc[i][j] = (f32x4){0.f, 0.f, 0.f, 0.f};
    gemm128_core(og + (long)mb * 128 * 128, wot, lsA, lsB, acc, t);

    const int lane = t & 63, w = t >> 6, l15 = lane & 15, hi = lane >> 4;
    const int wm = (w >> 1) * 64, wn = (w & 1) * 64;
    #pragma unroll
    for (int mf = 0; mf < 4; ++mf)
        #pragma unroll
        for (int nf = 0; nf < 4; ++nf)
            #pragma unroll
            for (int r = 0; r < 4; ++r) {
                long pos = (long)mb * 128 + wm + mf * 16 + hi * 4 + r;
                int n = wn + nf * 16 + l15;
                out[pos * CIN + n] = acc[mf][nf][r];
            }
}

// ---------------------------------------------------------------------------
extern "C" void kernel_launch(void* const* d_in, const int* in_sizes, int n_in,
                              void* d_out, int out_size, void* d_ws, size_t ws_size,
                              hipStream_t stream)
{
    const float* z    = (const float*)d_in[0];
    const float* mask = (const float*)d_in[1];
    const float* lnw  = (const float*)d_in[2];
    const float* lnb  = (const float*)d_in[3];
    const float* wtri = (const float*)d_in[4];
    const float* wq   = (const float*)d_in[5];
    const float* wk   = (const float*)d_in[6];
    const float* wv   = (const float*)d_in[7];
    const float* wg   = (const float*)d_in[8];
    const float* wo   = (const float*)d_in[9];
    float* out = (float*)d_out;

    char* ws = (char*)d_ws;
    size_t off = 0;
    auto carve = [&](size_t bytes) -> void* {
        void* p = ws + off; off += (bytes + 255) & ~size_t(255); return p;
    };
    const size_t nelem = (size_t)NPOS * CIN;   // 18,874,368
    unsigned short* zn  = (unsigned short*)carve(nelem * 2);   // reused as og
    unsigned short* qb  = (unsigned short*)carve(nelem * 2);
    unsigned short* kb  = (unsigned short*)carve(nelem * 2);
    unsigned short* vb  = (unsigned short*)carve(nelem * 2);
    unsigned short* gb  = (unsigned short*)carve(nelem * 2);
    unsigned short* ob  = (unsigned short*)carve(nelem * 2);
    unsigned short* trib = (unsigned short*)carve((size_t)NH * NPOS * 2);
    unsigned short* wcat = (unsigned short*)carve((size_t)4 * CIN * CIN * 2);
    unsigned short* wot  = (unsigned short*)carve((size_t)CIN * CIN * 2);
    (void)ws_size; (void)in_sizes; (void)n_in; (void)out_size;

    hipLaunchKernelGGL(ln_kernel, dim3(NPOS / 32), dim3(256), 0, stream,
                       z, lnw, lnb, wtri, zn, trib);
    hipLaunchKernelGGL(wconv_kernel, dim3(5), dim3(256), 0, stream,
                       wq, wk, wv, wg, wo, wcat, wot);
    hipLaunchKernelGGL(proj_gemm_kernel, dim3(NPOS / 128, 4), dim3(256), 0, stream,
                       zn, wcat, qb, kb, vb, gb);
    hipLaunchKernelGGL(attn_kernel, dim3(NN * NH), dim3(256), 0, stream,
                       qb, kb, vb, trib, mask, ob);
    hipLaunchKernelGGL(og_kernel, dim3(2048), dim3(256), 0, stream,
                       (const unsigned int*)ob, (const unsigned int*)gb, (unsigned int*)zn);
    hipLaunchKernelGGL(out_gemm_kernel, dim3(NPOS / 128), dim3(256), 0, stream,
                       (const unsigned short*)zn, wot, out);
}